// Round 6
// baseline (167.620 us; speedup 1.0000x reference)
//
#include <hip/hip_runtime.h>
#include <math.h>

namespace {
constexpr int BN = 512, HH = 64, WW = 128, CC = 3;
constexpr int OHH = 13, OWW = 26;
constexpr int NPOS = OHH * OWW;        // 338 positions per image
constexpr int FEATN = NPOS * 64;       // 21632
constexpr int KC = 256;                // K-chunk for fc0 GEMM
constexpr int NKS = (FEATN + KC - 1) / KC;  // 85
}

// ---------------------------------------------------------------------------
// K1: fused avgpool(3x3,s1,SAME,count-norm)->conv0(3x3,s5)->relu and
//     conv1(5x5,s5,padT0 B1 L1 R1)->relu, writing TRANSPOSED feat:
//     feat_T[(pos*64+ch)*512 + b].
// Grid is pos-major: p = pos*512 + b, so a wave's 64 lanes are consecutive b
// at the SAME (oh,ow): every store is 256B contiguous (full-line writes),
// and (oh,ow)-dependent masks are wave-uniform.
// ---------------------------------------------------------------------------
__global__ __launch_bounds__(256, 3) void k_feat(const float* __restrict__ x,
                                                 const float* __restrict__ w0,
                                                 const float* __restrict__ w1,
                                                 float* __restrict__ featT) {
  const int p = blockIdx.x * 256 + threadIdx.x;  // 0 .. 173055
  const int pos = p >> 9;                        // 0 .. 337 (uniform per block)
  const int b = p & 511;
  const int oh = pos / 26;
  const int ow = pos - oh * 26;
  const float* xb = x + (size_t)b * (HH * WW * CC);

  // footprint: rows oh*5-1 .. oh*5+4, cols ow*5-1 .. ow*5+3, zero-masked OOB
  float xv[6][15];
#pragma unroll
  for (int ri = 0; ri < 6; ++ri) {
    const int gr = oh * 5 - 1 + ri;
    const int grc = min(max(gr, 0), HH - 1);
    const bool rv = (gr >= 0) & (gr <= HH - 1);
    const float* rowp = xb + grc * (WW * CC);
#pragma unroll
    for (int pj = 0; pj < 5; ++pj) {
      const int gc = ow * 5 - 1 + pj;
      const int gcc = min(max(gc, 0), WW - 1);
      const bool v = rv & (gc >= 0) & (gc <= WW - 1);
      const float* pp = rowp + gcc * CC;
      const float f0 = pp[0], f1 = pp[1], f2 = pp[2];
      xv[ri][pj * 3 + 0] = v ? f0 : 0.f;
      xv[ri][pj * 3 + 1] = v ? f1 : 0.f;
      xv[ri][pj * 3 + 2] = v ? f2 : 0.f;
    }
  }

  // pooled taps for conv0 (TF avg_pool: normalize by valid-element count)
  float inv[3][3];
#pragma unroll
  for (int kh = 0; kh < 3; ++kh)
#pragma unroll
    for (int kw = 0; kw < 3; ++kw) {
      const int rc = 3 - ((oh == 0 && kh == 0) ? 1 : 0);
      int cc2 = 3;
      if (ow == 0 && kw == 0) cc2 = 2;
      if (ow == OWW - 1 && kw == 2) cc2 = 2;
      inv[kh][kw] = 1.0f / (float)(rc * cc2);
    }
  float pooled[27];
#pragma unroll
  for (int kh = 0; kh < 3; ++kh)
#pragma unroll
    for (int kw = 0; kw < 3; ++kw)
#pragma unroll
      for (int ic = 0; ic < 3; ++ic) {
        float s = 0.f;
#pragma unroll
        for (int dr = 0; dr < 3; ++dr)
#pragma unroll
          for (int dc = 0; dc < 3; ++dc)
            s += xv[kh + dr][(kw + dc) * 3 + ic];
        pooled[(kh * 3 + kw) * 3 + ic] = s * inv[kh][kw];
      }

  float* ft = featT + (size_t)pos * 64 * 512 + b;  // stride 512 between ch

  // conv0: weight addresses wave-uniform -> scalarized s_load
#pragma unroll 1
  for (int qg = 0; qg < 8; ++qg) {
    float a0 = 0.f, a1 = 0.f, a2 = 0.f, a3 = 0.f;
#pragma unroll
    for (int tap = 0; tap < 27; ++tap) {
      const float pv = pooled[tap];
      const float4 wv = *(const float4*)(w0 + tap * 32 + qg * 4);
      a0 += pv * wv.x; a1 += pv * wv.y; a2 += pv * wv.z; a3 += pv * wv.w;
    }
    ft[(size_t)(qg * 4 + 0) * 512] = fmaxf(a0, 0.f);
    ft[(size_t)(qg * 4 + 1) * 512] = fmaxf(a1, 0.f);
    ft[(size_t)(qg * 4 + 2) * 512] = fmaxf(a2, 0.f);
    ft[(size_t)(qg * 4 + 3) * 512] = fmaxf(a3, 0.f);
  }

  // conv1: rows oh*5+kh -> xv[kh+1], cols ow*5-1+kw -> pixel kw
#pragma unroll 1
  for (int qg = 0; qg < 8; ++qg) {
    float a0 = 0.f, a1 = 0.f, a2 = 0.f, a3 = 0.f;
#pragma unroll
    for (int kh = 0; kh < 5; ++kh)
#pragma unroll
      for (int kw = 0; kw < 5; ++kw)
#pragma unroll
        for (int ic = 0; ic < 3; ++ic) {
          const float pv = xv[kh + 1][kw * 3 + ic];
          const int tap = (kh * 5 + kw) * 3 + ic;
          const float4 wv = *(const float4*)(w1 + tap * 32 + qg * 4);
          a0 += pv * wv.x; a1 += pv * wv.y; a2 += pv * wv.z; a3 += pv * wv.w;
        }
    ft[(size_t)(32 + qg * 4 + 0) * 512] = fmaxf(a0, 0.f);
    ft[(size_t)(32 + qg * 4 + 1) * 512] = fmaxf(a1, 0.f);
    ft[(size_t)(32 + qg * 4 + 2) * 512] = fmaxf(a2, 0.f);
    ft[(size_t)(32 + qg * 4 + 3) * 512] = fmaxf(a3, 0.f);
  }
}

// ---------------------------------------------------------------------------
// K2: fc0 partial GEMM on TRANSPOSED feat. hid[m][n] = sum_k feat_T[k][m]*w[k][n].
// Thread owns one m with 32 fp32 accs; feat_T[k][:] loads are coalesced dwords;
// w rows are wave-uniform (scalarized). grid = 2 m-halves x 85 K-splits.
// ---------------------------------------------------------------------------
__global__ __launch_bounds__(256) void k_fc0(const float* __restrict__ featT,
                                             const float* __restrict__ w,
                                             float* __restrict__ part) {
  const int ks = blockIdx.x >> 1;
  const int mt = blockIdx.x & 1;
  const int m = mt * 256 + threadIdx.x;
  const int k0 = ks * KC;
  const int k1 = min(FEATN, k0 + KC);
  float acc[32];
#pragma unroll
  for (int n = 0; n < 32; ++n) acc[n] = 0.f;
  for (int kk = k0; kk < k1; ++kk) {
    const float f = featT[(size_t)kk * 512 + m];
    const float4* wr = (const float4*)(w + (size_t)kk * 32);
#pragma unroll
    for (int q = 0; q < 8; ++q) {
      const float4 wv = wr[q];
      acc[q * 4 + 0] += f * wv.x; acc[q * 4 + 1] += f * wv.y;
      acc[q * 4 + 2] += f * wv.z; acc[q * 4 + 3] += f * wv.w;
    }
  }
  float4* po = (float4*)(part + ((size_t)ks * 512 + m) * 32);
#pragma unroll
  for (int q = 0; q < 8; ++q)
    po[q] = make_float4(acc[q * 4], acc[q * 4 + 1], acc[q * 4 + 2], acc[q * 4 + 3]);
}

// ---------------------------------------------------------------------------
// K3: reduce 85 K-split partials + bias + tanh -> hid; fc1 + tanh -> theta
// ---------------------------------------------------------------------------
__global__ __launch_bounds__(256) void k_theta(const float* __restrict__ part,
                                               const float* __restrict__ b0,
                                               const float* __restrict__ w1,
                                               const float* __restrict__ b1,
                                               float* __restrict__ theta) {
  __shared__ float hid[8][32];
  const int t = threadIdx.x;
  const int bl = t >> 5, oc = t & 31;
  const int bb = blockIdx.x * 8 + bl;
  float s = 0.f;
  for (int ks = 0; ks < NKS; ++ks)
    s += part[(size_t)ks * 512 * 32 + bb * 32 + oc];
  hid[bl][oc] = tanhf(s + b0[oc]);
  __syncthreads();
  if (t < 48) {
    const int bl2 = t / 6, j = t - bl2 * 6;
    float s2 = b1[j];
#pragma unroll
    for (int o2 = 0; o2 < 32; ++o2) s2 += hid[bl2][o2] * w1[o2 * 6 + j];
    theta[(blockIdx.x * 8 + bl2) * 6 + j] = tanhf(s2);
  }
}

// ---------------------------------------------------------------------------
// K4: affine grid + bilinear sample (exact reference clip/extrapolate; Wd==1)
// ---------------------------------------------------------------------------
__global__ __launch_bounds__(256) void k_sample(const float* __restrict__ x,
                                                const float* __restrict__ theta,
                                                float* __restrict__ out) {
  const int b = blockIdx.x >> 3;
  const int seg = blockIdx.x & 7;
  __shared__ float th[6];
  if (threadIdx.x < 6) th[threadIdx.x] = theta[b * 6 + threadIdx.x];
  __syncthreads();
  const float t00 = th[0], t01 = th[1], t02 = th[2];
  const float t10 = th[3], t11 = th[4], t12 = th[5];
  const int idx = seg * 1024 + threadIdx.x * 4;  // pixel index within image
  const int i = idx >> 7, j0 = idx & 127;
  const float yt = (float)i * (2.0f / 63.0f) - 1.0f;
  const float* xb = x + (size_t)b * (HH * WW * CC);
  float res[12];
#pragma unroll
  for (int p = 0; p < 4; ++p) {
    const float xt = (float)(j0 + p) * (2.0f / 127.0f) - 1.0f;
    const float gx = (t00 * xt + t01 * yt + t02 + 1.0f) * 64.0f;
    const float gy = (t10 * xt + t11 * yt + t12 + 1.0f) * 32.0f;
    const float fx = floorf(gx), fy = floorf(gy);
    const float x0f = fminf(fmaxf(fx, 0.f), 126.f);
    const float x1f = fminf(fmaxf(fx + 1.f, 1.f), 127.f);
    const float y0f = fminf(fmaxf(fy, 0.f), 62.f);
    const float y1f = fminf(fmaxf(fy + 1.f, 1.f), 63.f);
    const float wx0 = x1f - gx, wx1 = gx - x0f;
    const float wy0 = y1f - gy, wy1 = gy - y0f;
    const int xi0 = (int)x0f, xi1 = (int)x1f;
    const int yi0 = (int)y0f, yi1 = (int)y1f;
    const float* q00 = xb + (yi0 * WW + xi0) * 3;
    const float* q01 = xb + (yi1 * WW + xi0) * 3;
    const float* q10 = xb + (yi0 * WW + xi1) * 3;
    const float* q11 = xb + (yi1 * WW + xi1) * 3;
#pragma unroll
    for (int c = 0; c < 3; ++c)
      res[p * 3 + c] = wx0 * (wy0 * q00[c] + wy1 * q01[c]) +
                       wx1 * (wy0 * q10[c] + wy1 * q11[c]);
  }
  float4* o = (float4*)(out + ((size_t)b * 8192 + idx) * 3);
  o[0] = make_float4(res[0], res[1], res[2], res[3]);
  o[1] = make_float4(res[4], res[5], res[6], res[7]);
  o[2] = make_float4(res[8], res[9], res[10], res[11]);
}

extern "C" void kernel_launch(void* const* d_in, const int* in_sizes, int n_in,
                              void* d_out, int out_size, void* d_ws, size_t ws_size,
                              hipStream_t stream) {
  (void)in_sizes; (void)n_in; (void)out_size; (void)ws_size;
  const float* x   = (const float*)d_in[0];
  const float* w0  = (const float*)d_in[1];
  const float* w1  = (const float*)d_in[2];
  const float* fw0 = (const float*)d_in[3];
  const float* fb0 = (const float*)d_in[4];
  const float* fw1 = (const float*)d_in[5];
  const float* fb1 = (const float*)d_in[6];
  float* outp = (float*)d_out;
  // d_out doubles as scratch: feat_T (44.30 MB = 11,075,584 floats) + fc0
  // partials (85*512*32 = 1,392,640 floats) = 12,468,224 <= 12,582,912 floats.
  // Both fully consumed before K4 overwrites every output element.
  float* featT = outp;
  float* part  = outp + (size_t)BN * FEATN;
  float* theta = (float*)d_ws;  // 12 KB — survives K4's output writes
  k_feat  <<<(BN * NPOS) / 256, 256, 0, stream>>>(x, w0, w1, featT);
  k_fc0   <<<2 * NKS, 256, 0, stream>>>(featT, fw0, part);
  k_theta <<<64, 256, 0, stream>>>(part, fb0, fw1, fb1, theta);
  k_sample<<<BN * 8, 256, 0, stream>>>(x, theta, outp);
}

// Round 8
// 138.803 us; speedup vs baseline: 1.2076x; 1.2076x over previous
//
#include <hip/hip_runtime.h>
#include <math.h>

namespace {
constexpr int BN = 512, HH = 64, WW = 128, CC = 3;
constexpr int OHH = 13, OWW = 26;
constexpr int NPOS = OHH * OWW;        // 338 positions per image
constexpr int FEATN = NPOS * 64;       // 21632
constexpr int KC = 256;                // K-chunk for fc0 GEMM
constexpr int NKS = (FEATN + KC - 1) / KC;  // 85 (last chunk = 128)
}

// ---------------------------------------------------------------------------
// K1: fused avgpool(3x3,s1,SAME,count-norm)->conv0(3x3,s5)->relu and
//     conv1(5x5,s5,padT0 B1 L1 R1)->relu, writing TRANSPOSED feat:
//     feat_T[(pos*64+ch)*512 + b].
// Grid is pos-major: wave lanes = consecutive b at the SAME (oh,ow) ->
// 256B full-line stores, wave-uniform masks.
// ---------------------------------------------------------------------------
__global__ __launch_bounds__(256, 3) void k_feat(const float* __restrict__ x,
                                                 const float* __restrict__ w0,
                                                 const float* __restrict__ w1,
                                                 float* __restrict__ featT) {
  const int p = blockIdx.x * 256 + threadIdx.x;  // 0 .. 173055
  const int pos = p >> 9;                        // 0 .. 337 (uniform per block)
  const int b = p & 511;
  const int oh = pos / 26;
  const int ow = pos - oh * 26;
  const float* xb = x + (size_t)b * (HH * WW * CC);

  // footprint: rows oh*5-1 .. oh*5+4, cols ow*5-1 .. ow*5+3, zero-masked OOB
  float xv[6][15];
#pragma unroll
  for (int ri = 0; ri < 6; ++ri) {
    const int gr = oh * 5 - 1 + ri;
    const int grc = min(max(gr, 0), HH - 1);
    const bool rv = (gr >= 0) & (gr <= HH - 1);
    const float* rowp = xb + grc * (WW * CC);
#pragma unroll
    for (int pj = 0; pj < 5; ++pj) {
      const int gc = ow * 5 - 1 + pj;
      const int gcc = min(max(gc, 0), WW - 1);
      const bool v = rv & (gc >= 0) & (gc <= WW - 1);
      const float* pp = rowp + gcc * CC;
      const float f0 = pp[0], f1 = pp[1], f2 = pp[2];
      xv[ri][pj * 3 + 0] = v ? f0 : 0.f;
      xv[ri][pj * 3 + 1] = v ? f1 : 0.f;
      xv[ri][pj * 3 + 2] = v ? f2 : 0.f;
    }
  }

  // pooled taps for conv0 (TF avg_pool: normalize by valid-element count)
  float inv[3][3];
#pragma unroll
  for (int kh = 0; kh < 3; ++kh)
#pragma unroll
    for (int kw = 0; kw < 3; ++kw) {
      const int rc = 3 - ((oh == 0 && kh == 0) ? 1 : 0);
      int cc2 = 3;
      if (ow == 0 && kw == 0) cc2 = 2;
      if (ow == OWW - 1 && kw == 2) cc2 = 2;
      inv[kh][kw] = 1.0f / (float)(rc * cc2);
    }
  float pooled[27];
#pragma unroll
  for (int kh = 0; kh < 3; ++kh)
#pragma unroll
    for (int kw = 0; kw < 3; ++kw)
#pragma unroll
      for (int ic = 0; ic < 3; ++ic) {
        float s = 0.f;
#pragma unroll
        for (int dr = 0; dr < 3; ++dr)
#pragma unroll
          for (int dc = 0; dc < 3; ++dc)
            s += xv[kh + dr][(kw + dc) * 3 + ic];
        pooled[(kh * 3 + kw) * 3 + ic] = s * inv[kh][kw];
      }

  float* ft = featT + (size_t)pos * 64 * 512 + b;  // stride 512 between ch

  // conv0: weight addresses wave-uniform -> scalarized s_load
#pragma unroll 1
  for (int qg = 0; qg < 8; ++qg) {
    float a0 = 0.f, a1 = 0.f, a2 = 0.f, a3 = 0.f;
#pragma unroll
    for (int tap = 0; tap < 27; ++tap) {
      const float pv = pooled[tap];
      const float4 wv = *(const float4*)(w0 + tap * 32 + qg * 4);
      a0 += pv * wv.x; a1 += pv * wv.y; a2 += pv * wv.z; a3 += pv * wv.w;
    }
    ft[(size_t)(qg * 4 + 0) * 512] = fmaxf(a0, 0.f);
    ft[(size_t)(qg * 4 + 1) * 512] = fmaxf(a1, 0.f);
    ft[(size_t)(qg * 4 + 2) * 512] = fmaxf(a2, 0.f);
    ft[(size_t)(qg * 4 + 3) * 512] = fmaxf(a3, 0.f);
  }

  // conv1: rows oh*5+kh -> xv[kh+1], cols ow*5-1+kw -> pixel kw
#pragma unroll 1
  for (int qg = 0; qg < 8; ++qg) {
    float a0 = 0.f, a1 = 0.f, a2 = 0.f, a3 = 0.f;
#pragma unroll
    for (int kh = 0; kh < 5; ++kh)
#pragma unroll
      for (int kw = 0; kw < 5; ++kw)
#pragma unroll
        for (int ic = 0; ic < 3; ++ic) {
          const float pv = xv[kh + 1][kw * 3 + ic];
          const int tap = (kh * 5 + kw) * 3 + ic;
          const float4 wv = *(const float4*)(w1 + tap * 32 + qg * 4);
          a0 += pv * wv.x; a1 += pv * wv.y; a2 += pv * wv.z; a3 += pv * wv.w;
        }
    ft[(size_t)(32 + qg * 4 + 0) * 512] = fmaxf(a0, 0.f);
    ft[(size_t)(32 + qg * 4 + 1) * 512] = fmaxf(a1, 0.f);
    ft[(size_t)(32 + qg * 4 + 2) * 512] = fmaxf(a2, 0.f);
    ft[(size_t)(32 + qg * 4 + 3) * 512] = fmaxf(a3, 0.f);
  }
}

// ---------------------------------------------------------------------------
// K2: fc0 partial GEMM on feat_T. part[ks][m][n] = sum_{k in chunk} feat_T[k][m]*w[k][n].
// Block = 4 waves: wave og owns n-octet og*8..+7, lane owns m = sub*64+lane.
// featT loads 256B/wave coalesced (shared by the 4 og-waves via L1); weight
// rows wave-uniform (s_load); acc[8] + unroll-8 keeps ~8 loads in flight.
// grid = NKS ksplits x 8 m-strips = 680 blocks.
// ---------------------------------------------------------------------------
__global__ __launch_bounds__(256) void k_fc0(const float* __restrict__ featT,
                                             const float* __restrict__ w,
                                             float* __restrict__ part) {
  const int ks = blockIdx.x >> 3;
  const int sub = blockIdx.x & 7;
  const int lane = threadIdx.x & 63;
  const int og = threadIdx.x >> 6;       // 0..3
  const int m = sub * 64 + lane;
  const int k0 = ks * KC;
  const int kcnt = min(KC, FEATN - k0);  // 256, or 128 for last ksplit
  const float* fp = featT + (size_t)k0 * 512 + m;
  const float* wp = w + (size_t)k0 * 32 + og * 8;
  float acc[8] = {0.f, 0.f, 0.f, 0.f, 0.f, 0.f, 0.f, 0.f};
#pragma unroll 8
  for (int kk = 0; kk < kcnt; ++kk) {
    const float f = fp[(size_t)kk * 512];
    const float4 wa = *(const float4*)(wp + (size_t)kk * 32);
    const float4 wb = *(const float4*)(wp + (size_t)kk * 32 + 4);
    acc[0] += f * wa.x; acc[1] += f * wa.y;
    acc[2] += f * wa.z; acc[3] += f * wa.w;
    acc[4] += f * wb.x; acc[5] += f * wb.y;
    acc[6] += f * wb.z; acc[7] += f * wb.w;
  }
  float* po = part + ((size_t)ks * 512 + m) * 32 + og * 8;
  *(float4*)po = make_float4(acc[0], acc[1], acc[2], acc[3]);
  *(float4*)(po + 4) = make_float4(acc[4], acc[5], acc[6], acc[7]);
}

// ---------------------------------------------------------------------------
// K3: reduce 85 K-split partials + bias + tanh -> hid; fc1 + tanh -> theta
// ---------------------------------------------------------------------------
__global__ __launch_bounds__(256) void k_theta(const float* __restrict__ part,
                                               const float* __restrict__ b0,
                                               const float* __restrict__ w1,
                                               const float* __restrict__ b1,
                                               float* __restrict__ theta) {
  __shared__ float hid[8][32];
  const int t = threadIdx.x;
  const int bl = t >> 5, oc = t & 31;
  const int bb = blockIdx.x * 8 + bl;
  float s = 0.f;
  for (int ks = 0; ks < NKS; ++ks)
    s += part[(size_t)ks * 512 * 32 + bb * 32 + oc];
  hid[bl][oc] = tanhf(s + b0[oc]);
  __syncthreads();
  if (t < 48) {
    const int bl2 = t / 6, j = t - bl2 * 6;
    float s2 = b1[j];
#pragma unroll
    for (int o2 = 0; o2 < 32; ++o2) s2 += hid[bl2][o2] * w1[o2 * 6 + j];
    theta[(blockIdx.x * 8 + bl2) * 6 + j] = tanhf(s2);
  }
}

// ---------------------------------------------------------------------------
// K4: affine grid + bilinear sample (exact reference clip/extrapolate; Wd==1)
// ---------------------------------------------------------------------------
__global__ __launch_bounds__(256) void k_sample(const float* __restrict__ x,
                                                const float* __restrict__ theta,
                                                float* __restrict__ out) {
  const int b = blockIdx.x >> 3;
  const int seg = blockIdx.x & 7;
  __shared__ float th[6];
  if (threadIdx.x < 6) th[threadIdx.x] = theta[b * 6 + threadIdx.x];
  __syncthreads();
  const float t00 = th[0], t01 = th[1], t02 = th[2];
  const float t10 = th[3], t11 = th[4], t12 = th[5];
  const int idx = seg * 1024 + threadIdx.x * 4;  // pixel index within image
  const int i = idx >> 7, j0 = idx & 127;
  const float yt = (float)i * (2.0f / 63.0f) - 1.0f;
  const float* xb = x + (size_t)b * (HH * WW * CC);
  float res[12];
#pragma unroll
  for (int p = 0; p < 4; ++p) {
    const float xt = (float)(j0 + p) * (2.0f / 127.0f) - 1.0f;
    const float gx = (t00 * xt + t01 * yt + t02 + 1.0f) * 64.0f;
    const float gy = (t10 * xt + t11 * yt + t12 + 1.0f) * 32.0f;
    const float fx = floorf(gx), fy = floorf(gy);
    const float x0f = fminf(fmaxf(fx, 0.f), 126.f);
    const float x1f = fminf(fmaxf(fx + 1.f, 1.f), 127.f);
    const float y0f = fminf(fmaxf(fy, 0.f), 62.f);
    const float y1f = fminf(fmaxf(fy + 1.f, 1.f), 63.f);
    const float wx0 = x1f - gx, wx1 = gx - x0f;
    const float wy0 = y1f - gy, wy1 = gy - y0f;
    const int xi0 = (int)x0f, xi1 = (int)x1f;
    const int yi0 = (int)y0f, yi1 = (int)y1f;
    const float* q00 = xb + (yi0 * WW + xi0) * 3;
    const float* q01 = xb + (yi1 * WW + xi0) * 3;
    const float* q10 = xb + (yi0 * WW + xi1) * 3;
    const float* q11 = xb + (yi1 * WW + xi1) * 3;
#pragma unroll
    for (int c = 0; c < 3; ++c)
      res[p * 3 + c] = wx0 * (wy0 * q00[c] + wy1 * q01[c]) +
                       wx1 * (wy0 * q10[c] + wy1 * q11[c]);
  }
  float4* o = (float4*)(out + ((size_t)b * 8192 + idx) * 3);
  o[0] = make_float4(res[0], res[1], res[2], res[3]);
  o[1] = make_float4(res[4], res[5], res[6], res[7]);
  o[2] = make_float4(res[8], res[9], res[10], res[11]);
}

extern "C" void kernel_launch(void* const* d_in, const int* in_sizes, int n_in,
                              void* d_out, int out_size, void* d_ws, size_t ws_size,
                              hipStream_t stream) {
  (void)in_sizes; (void)n_in; (void)out_size; (void)ws_size;
  const float* x   = (const float*)d_in[0];
  const float* w0  = (const float*)d_in[1];
  const float* w1  = (const float*)d_in[2];
  const float* fw0 = (const float*)d_in[3];
  const float* fb0 = (const float*)d_in[4];
  const float* fw1 = (const float*)d_in[5];
  const float* fb1 = (const float*)d_in[6];
  float* outp = (float*)d_out;
  // d_out doubles as scratch: feat_T (11,075,584 floats) + fc0 partials
  // (85*512*32 = 1,392,640) = 12,468,224 <= 12,582,912 floats of d_out.
  // Both fully consumed before K4 overwrites every output element.
  float* featT = outp;
  float* part  = outp + (size_t)BN * FEATN;
  float* theta = (float*)d_ws;  // 12 KB — survives K4's output writes
  k_feat  <<<(BN * NPOS) / 256, 256, 0, stream>>>(x, w0, w1, featT);
  k_fc0   <<<NKS * 8, 256, 0, stream>>>(featT, fw0, part);
  k_theta <<<64, 256, 0, stream>>>(part, fb0, fw1, fb1, theta);
  k_sample<<<BN * 8, 256, 0, stream>>>(x, theta, outp);
}